// Round 1
// baseline (554.689 us; speedup 1.0000x reference)
//
#include <hip/hip_runtime.h>
#include <stdint.h>
#include <stddef.h>

// VectorQuantization — N=32768, K=8192, D=256 fp32 -> int32 argmin.
// Round 5: pipeline the staging (T3 minimum-2-phase). BK=32-half chunks,
// TWO 32KB LDS buffers in the same 64KB footprint (2 blocks/CU kept):
//   STAGE(next chunk -> other buffer); COMPUTE(current); __syncthreads()
// so the global_load_lds latency flies under the ~1860-cyc MFMA phase instead
// of serializing with it (the m97 barrier-drain stall = the missing 50% of
// MfmaUtil). With 64B row pitch the (row&1) bit alternates LDS bank halves,
// so a LINEAR layout is already 8 words/bank on ds_read_b128 -> the XOR
// swizzle from round 4 is dropped on both sides. K-slice accumulation order
// is unchanged -> bit-identical distances to round 4.
// prep: split(x) + split(codes)+cnorms fused into ONE launch (5 -> 3 kernels).
// Fallback to the (passing) round-3 kernel if ws_size < 43MB.

#define N_PTS 32768
#define K_CB  8192
#define D_DIM 256
#define TM 128
#define TN 128
#define SPLITK 4
#define KCHUNK (K_CB / SPLITK)   // 2048
#define NTILES (KCHUNK / TN)     // 16
#define NCHUNKS (NTILES * 8)     // 128 BK=32 chunks per block

// fast-path ws layout (byte offsets; all 16B-aligned)
#define WS_XH   0
#define WS_XL   (WS_XH + N_PTS * D_DIM * 2)
#define WS_CH   (WS_XL + N_PTS * D_DIM * 2)
#define WS_CL   (WS_CH + K_CB * D_DIM * 2)
#define WS_C2   (WS_CL + K_CB * D_DIM * 2)
#define WS_PD   (WS_C2 + K_CB * 4)
#define WS_PI   (WS_PD + SPLITK * N_PTS * 4)
#define WS_END  (WS_PI + SPLITK * N_PTS * 4)   // 43,024,384 B

typedef _Float16 half4v __attribute__((ext_vector_type(4)));
typedef _Float16 half8v __attribute__((ext_vector_type(8)));
typedef float    f32x4  __attribute__((ext_vector_type(4)));

__device__ __forceinline__ void gld16(const void* g, void* l) {
    __builtin_amdgcn_global_load_lds(
        (const __attribute__((address_space(1))) void*)g,
        (__attribute__((address_space(3))) void*)l, 16, 0, 0);
}

// ---------------- preprocessing (fused: split x, split codes + norms) ------

#define XBLOCKS (N_PTS * D_DIM / 4 / 256)   // 8192
#define CBLOCKS (K_CB * D_DIM / 4 / 256)    // 2048

__global__ void __launch_bounds__(256)
prep_kernel(const float* __restrict__ x, const float* __restrict__ vecs,
            _Float16* __restrict__ xh, _Float16* __restrict__ xl,
            _Float16* __restrict__ ch, _Float16* __restrict__ cl,
            float* __restrict__ c2) {
    const int b = blockIdx.x;
    if (b < XBLOCKS) {
        const int i = b * 256 + threadIdx.x;           // one float4 per thread
        const float4 v = ((const float4*)x)[i];
        half4v h = {(_Float16)v.x, (_Float16)v.y, (_Float16)v.z, (_Float16)v.w};
        half4v l = {(_Float16)((v.x - (float)h[0]) * 2048.0f),
                    (_Float16)((v.y - (float)h[1]) * 2048.0f),
                    (_Float16)((v.z - (float)h[2]) * 2048.0f),
                    (_Float16)((v.w - (float)h[3]) * 2048.0f)};
        *(half4v*)(xh + (size_t)i * 4) = h;
        *(half4v*)(xl + (size_t)i * 4) = l;
    } else {
        const int i = (b - XBLOCKS) * 256 + threadIdx.x;
        const float4 v = ((const float4*)vecs)[i];
        half4v h = {(_Float16)v.x, (_Float16)v.y, (_Float16)v.z, (_Float16)v.w};
        half4v l = {(_Float16)((v.x - (float)h[0]) * 2048.0f),
                    (_Float16)((v.y - (float)h[1]) * 2048.0f),
                    (_Float16)((v.z - (float)h[2]) * 2048.0f),
                    (_Float16)((v.w - (float)h[3]) * 2048.0f)};
        *(half4v*)(ch + (size_t)i * 4) = h;
        *(half4v*)(cl + (size_t)i * 4) = l;
        // one wave == one code row (64 lanes x float4 = 256 floats) -> norm.
        // identical reduction tree to round-4 cnorms_kernel (bit-identical c2).
        float s = v.x * v.x + v.y * v.y + v.z * v.z + v.w * v.w;
#pragma unroll
        for (int off = 32; off > 0; off >>= 1) s += __shfl_down(s, off, 64);
        if ((threadIdx.x & 63) == 0) c2[i >> 6] = s;
    }
}

// kept for the fallback path
__global__ void __launch_bounds__(256)
cnorms_kernel(const float* __restrict__ vecs, float* __restrict__ c2) {
    int gwave = (blockIdx.x * 256 + threadIdx.x) >> 6;   // one wave per code row
    int lane  = threadIdx.x & 63;
    const float* src = vecs + (size_t)gwave * D_DIM;
    float4 v = ((const float4*)src)[lane];
    float s = v.x * v.x + v.y * v.y + v.z * v.z + v.w * v.w;
#pragma unroll
    for (int off = 32; off > 0; off >>= 1) s += __shfl_down(s, off, 64);
    if (lane == 0) c2[gwave] = s;
}

// ---------------- fast main kernel ----------------

__global__ void __launch_bounds__(256, 2)
vq_main_fast(const _Float16* __restrict__ xh_g, const _Float16* __restrict__ xl_g,
             const _Float16* __restrict__ ch_g, const _Float16* __restrict__ cl_g,
             const float* __restrict__ c2, float* __restrict__ pd, int* __restrict__ pi) {
    // two 32KB buffers; per buffer: xh [0,8K) xl [8K,16K) ch [16K,24K) cl [24K,32K)
    // rows are 64B (32 halves) -> linear layout is conflict-free (row&1 flips
    // bank half; fr x g spreads reads over all 8 16B bank groups).
    __shared__ __align__(16) char lds[65536];

    const int t    = threadIdx.x;
    const int lane = t & 63;
    const int wv   = t >> 6;
    const int wy   = wv >> 1, wx = wv & 1;   // wave quadrant of 128x128
    const int fr   = lane & 15;              // row/col within 16x16 tile
    const int g    = lane >> 4;              // k-group 0..3

    const int split = blockIdx.x & (SPLITK - 1);
    const int pbase = (blockIdx.x >> 2) * TM;
    const int kbase = split * KCHUNK;

    // staging: one gld16 covers 16 rows x 64B, linear both sides.
    // lane i -> row i>>2, 16B slot i&3 (LDS dest = base + lane*16 matches).
    const int srowoff = (lane >> 2) * (D_DIM * 2) + ((lane & 3) << 4);
    const char* xh_s = (const char*)xh_g + (size_t)(pbase + wv * 32) * (D_DIM * 2) + srowoff;
    const char* xl_s = (const char*)xl_g + (size_t)(pbase + wv * 32) * (D_DIM * 2) + srowoff;
    const char* ch_s = (const char*)ch_g + (size_t)(kbase + wv * 32) * (D_DIM * 2) + srowoff;
    const char* cl_s = (const char*)cl_g + (size_t)(kbase + wv * 32) * (D_DIM * 2) + srowoff;
    const int stA = wv * 32 * 64;            // wave staging base within a region

    // fragment LDS byte offsets (within a buffer): row*64 + g*16
    int aoff[4], boff[4];
#pragma unroll
    for (int i = 0; i < 4; ++i) {
        aoff[i] = (wy * 64 + i * 16 + fr) * 64 + (g << 4);
        boff[i] = 16384 + (wx * 64 + i * 16 + fr) * 64 + (g << 4);
    }

    f32x4 acc[4][4];

    // chunk c = kt*8 + dkc; buffer parity = c&1. 8 gld16 per wave per chunk.
    auto STAGE = [&](char* L, int c) {
        const size_t kofs = (size_t)(c >> 3) * (TN * D_DIM * 2);   // kt tile
        const int gofs = (c & 7) * 64;                             // byte offset in row
#pragma unroll
        for (int q = 0; q < 2; ++q) {
            gld16(xh_s + q * 8192 + gofs, L +         stA + q * 1024);
            gld16(xl_s + q * 8192 + gofs, L +  8192 + stA + q * 1024);
            gld16(ch_s + kofs + q * 8192 + gofs, L + 16384 + stA + q * 1024);
            gld16(cl_s + kofs + q * 8192 + gofs, L + 24576 + stA + q * 1024);
        }
    };

    auto COMPUTE = [&](const char* L) {
        half8v a1[4], a2[4], a3[4];
#pragma unroll
        for (int i = 0; i < 4; ++i) {
            const char* p = L + aoff[i];
            a1[i] = *(const half8v*)p;                  // xh
            a3[i] = *(const half8v*)(p + 8192);         // xl*2^11
            a2[i] = a1[i] * (_Float16)4.8828125e-4f;    // xh*2^-11
        }
#pragma unroll
        for (int j = 0; j < 4; ++j) {
            const char* p = L + boff[j];
            half8v b1 = *(const half8v*)p;              // ch
            half8v b2 = *(const half8v*)(p + 8192);     // cl*2^11
            half8v b3 = b1 * (_Float16)4.8828125e-4f;   // ch*2^-11
#pragma unroll
            for (int i = 0; i < 4; ++i) {
                acc[i][j] = __builtin_amdgcn_mfma_f32_16x16x32_f16(a1[i], b1, acc[i][j], 0, 0, 0);
                acc[i][j] = __builtin_amdgcn_mfma_f32_16x16x32_f16(a2[i], b2, acc[i][j], 0, 0, 0);
                acc[i][j] = __builtin_amdgcn_mfma_f32_16x16x32_f16(a3[i], b3, acc[i][j], 0, 0, 0);
            }
        }
    };

    float best[16];
    int   bidx[16];
#pragma unroll
    for (int i = 0; i < 16; ++i) { best[i] = 3.4e38f; bidx[i] = 0; }

    STAGE(lds, 0);
    __syncthreads();

#pragma unroll 1
    for (int kt = 0; kt < NTILES; ++kt) {
#pragma unroll
        for (int i = 0; i < 4; ++i)
#pragma unroll
            for (int j = 0; j < 4; ++j) {
                f32x4 z = {0.f, 0.f, 0.f, 0.f};
                acc[i][j] = z;
            }

#pragma unroll 1
        for (int du = 0; du < 4; ++du) {
            const int c = kt * 8 + du * 2;
            // even chunk: compute buf0 while buf1's data flies in
            if (c + 1 < NCHUNKS) STAGE(lds + 32768, c + 1);
            COMPUTE(lds);
            __syncthreads();                  // drains vmcnt: c+1 is ready
            // odd chunk: compute buf1 while buf0's data flies in
            if (c + 2 < NCHUNKS) STAGE(lds, c + 2);
            COMPUTE(lds + 32768);
            __syncthreads();                  // drains vmcnt: c+2 is ready
        }

        // merge tile into running argmin; ascending j + strict < == np first-min
        const int ktbase = kbase + kt * TN;
#pragma unroll
        for (int j = 0; j < 4; ++j) {
            const int cg = ktbase + wx * 64 + j * 16 + fr;
            const float c2v = c2[cg];
#pragma unroll
            for (int i = 0; i < 4; ++i)
#pragma unroll
                for (int r = 0; r < 4; ++r) {
                    const float v = fmaf(-2.0f, acc[i][j][r], c2v);
                    const int s = i * 4 + r;
                    if (v < best[s]) { best[s] = v; bidx[s] = cg; }
                }
        }
    }

    // reduce across the 16 lanes holding each point row, then the 2 wave-cols
    __syncthreads();
    float* rd = (float*)lds;          // 128 x 2 floats
    int*   ri = (int*)lds + 256;      // 128 x 2 ints
#pragma unroll
    for (int i = 0; i < 4; ++i)
#pragma unroll
        for (int r = 0; r < 4; ++r) {
            float bv = best[i * 4 + r];
            int   bi = bidx[i * 4 + r];
#pragma unroll
            for (int off = 1; off < 16; off <<= 1) {
                const float ov = __shfl_xor(bv, off, 64);
                const int   oi = __shfl_xor(bi, off, 64);
                if (ov < bv || (ov == bv && oi < bi)) { bv = ov; bi = oi; }
            }
            if (fr == 0) {
                const int rowl = wy * 64 + i * 16 + g * 4 + r;
                rd[rowl * 2 + wx] = bv;
                ri[rowl * 2 + wx] = bi;
            }
        }
    __syncthreads();
    if (t < TM) {
        float b0 = rd[t * 2];
        int   i0 = ri[t * 2];
        const float b1 = rd[t * 2 + 1];
        const int   i1 = ri[t * 2 + 1];
        if (b1 < b0 || (b1 == b0 && i1 < i0)) { b0 = b1; i0 = i1; }
        pd[split * N_PTS + pbase + t] = b0;
        pi[split * N_PTS + pbase + t] = i0;
    }
}

// ---------------- fallback (round-3, passing) ----------------

#define BK 32
#define LS (BK + 4)

__device__ inline half8v load8(const _Float16* p) {
    half4v a = *(const half4v*)p;
    half4v b = *(const half4v*)(p + 4);
    return __builtin_shufflevector(a, b, 0, 1, 2, 3, 4, 5, 6, 7);
}

struct Trip { _Float16 h, s2, l2; };

__device__ inline Trip cvt3(float v) {
    Trip t;
    _Float16 hh = (_Float16)v;
    float hf = (float)hh;
    t.h  = hh;
    t.s2 = (_Float16)(hf * 4.8828125e-4f);
    t.l2 = (_Float16)((v - hf) * 2048.0f);
    return t;
}

__global__ void __launch_bounds__(256, 2)
vq_main_v3(const float* __restrict__ x, const float* __restrict__ vecs,
           const float* __restrict__ c2, float* __restrict__ pd, int* __restrict__ pi) {
    __shared__ _Float16 lds[6 * TM * LS];
    _Float16* xh  = lds;
    _Float16* xs2 = lds + 1 * TM * LS;
    _Float16* xl2 = lds + 2 * TM * LS;
    _Float16* ch  = lds + 3 * TM * LS;
    _Float16* cl2 = lds + 4 * TM * LS;
    _Float16* cs2 = lds + 5 * TM * LS;

    const int t     = threadIdx.x;
    const int split = blockIdx.x & (SPLITK - 1);
    const int pbase = (blockIdx.x >> 2) * TM;
    const int kbase = split * KCHUNK;

    const int lane = t & 63;
    const int wv   = t >> 6;
    const int wy   = wv >> 1, wx = wv & 1;
    const int fr   = lane & 15;
    const int g    = lane >> 4;
    const int kb   = g * 8;

    const int srow = t >> 3;
    const int sc4  = (t & 7) * 4;

    float best[16];
    int   bidx[16];
#pragma unroll
    for (int i = 0; i < 16; ++i) { best[i] = 3.4e38f; bidx[i] = 0; }

    for (int kt = 0; kt < NTILES; ++kt) {
        const int ktbase = kbase + kt * TN;
        f32x4 acc[4][4];
#pragma unroll
        for (int i = 0; i < 4; ++i)
#pragma unroll
            for (int j = 0; j < 4; ++j) {
                f32x4 z = {0.f, 0.f, 0.f, 0.f};
                acc[i][j] = z;
            }
        for (int dk = 0; dk < D_DIM; dk += BK) {
            __syncthreads();
#pragma unroll
            for (int p = 0; p < 4; ++p) {
                const int row = srow + p * 32;
                const float4 v = *(const float4*)&x[(size_t)(pbase + row) * D_DIM + dk + sc4];
                const Trip t0 = cvt3(v.x), t1 = cvt3(v.y), t2 = cvt3(v.z), t3 = cvt3(v.w);
                half4v h  = {t0.h,  t1.h,  t2.h,  t3.h};
                half4v s2 = {t0.s2, t1.s2, t2.s2, t3.s2};
                half4v l2 = {t0.l2, t1.l2, t2.l2, t3.l2};
                *(half4v*)&xh [row * LS + sc4] = h;
                *(half4v*)&xs2[row * LS + sc4] = s2;
                *(half4v*)&xl2[row * LS + sc4] = l2;
                const float4 w = *(const float4*)&vecs[(size_t)(ktbase + row) * D_DIM + dk + sc4];
                const Trip u0 = cvt3(w.x), u1 = cvt3(w.y), u2 = cvt3(w.z), u3 = cvt3(w.w);
                half4v hc = {u0.h,  u1.h,  u2.h,  u3.h};
                half4v sc = {u0.s2, u1.s2, u2.s2, u3.s2};
                half4v lc = {u0.l2, u1.l2, u2.l2, u3.l2};
                *(half4v*)&ch [row * LS + sc4] = hc;
                *(half4v*)&cs2[row * LS + sc4] = sc;
                *(half4v*)&cl2[row * LS + sc4] = lc;
            }
            __syncthreads();
            half8v a1[4], a2[4], a3[4], b1[4], b2[4], b3[4];
#pragma unroll
            for (int i = 0; i < 4; ++i) {
                const int aoff = (wy * 64 + i * 16 + fr) * LS + kb;
                a1[i] = load8(&xh [aoff]);
                a2[i] = load8(&xs2[aoff]);
                a3[i] = load8(&xl2[aoff]);
                const int boff2 = (wx * 64 + i * 16 + fr) * LS + kb;
                b1[i] = load8(&ch [boff2]);
                b2[i] = load8(&cl2[boff2]);
                b3[i] = load8(&cs2[boff2]);
            }
#pragma unroll
            for (int i = 0; i < 4; ++i)
#pragma unroll
                for (int j = 0; j < 4; ++j) {
                    acc[i][j] = __builtin_amdgcn_mfma_f32_16x16x32_f16(a1[i], b1[j], acc[i][j], 0, 0, 0);
                    acc[i][j] = __builtin_amdgcn_mfma_f32_16x16x32_f16(a2[i], b2[j], acc[i][j], 0, 0, 0);
                    acc[i][j] = __builtin_amdgcn_mfma_f32_16x16x32_f16(a3[i], b3[j], acc[i][j], 0, 0, 0);
                }
        }
#pragma unroll
        for (int j = 0; j < 4; ++j) {
            const int cg = ktbase + wx * 64 + j * 16 + fr;
            const float c2v = c2[cg];
#pragma unroll
            for (int i = 0; i < 4; ++i)
#pragma unroll
                for (int r = 0; r < 4; ++r) {
                    const float v = fmaf(-2.0f, acc[i][j][r], c2v);
                    const int s = i * 4 + r;
                    if (v < best[s]) { best[s] = v; bidx[s] = cg; }
                }
        }
    }
    __syncthreads();
    float* rd = (float*)lds;
    int*   ri = (int*)lds + 256;
#pragma unroll
    for (int i = 0; i < 4; ++i)
#pragma unroll
        for (int r = 0; r < 4; ++r) {
            float bv = best[i * 4 + r];
            int   bi = bidx[i * 4 + r];
#pragma unroll
            for (int off = 1; off < 16; off <<= 1) {
                const float ov = __shfl_xor(bv, off, 64);
                const int   oi = __shfl_xor(bi, off, 64);
                if (ov < bv || (ov == bv && oi < bi)) { bv = ov; bi = oi; }
            }
            if (fr == 0) {
                const int rowl = wy * 64 + i * 16 + g * 4 + r;
                rd[rowl * 2 + wx] = bv;
                ri[rowl * 2 + wx] = bi;
            }
        }
    __syncthreads();
    if (t < TM) {
        float b0 = rd[t * 2];
        int   i0 = ri[t * 2];
        const float b1 = rd[t * 2 + 1];
        const int   i1 = ri[t * 2 + 1];
        if (b1 < b0 || (b1 == b0 && i1 < i0)) { b0 = b1; i0 = i1; }
        pd[split * N_PTS + pbase + t] = b0;
        pi[split * N_PTS + pbase + t] = i0;
    }
}

// ---------------- combine ----------------

__global__ void __launch_bounds__(256)
vq_combine(const float* __restrict__ pd, const int* __restrict__ pi,
           int* __restrict__ out) {
    const int p = blockIdx.x * 256 + threadIdx.x;
    float bb = pd[p];
    int   bi = pi[p];
#pragma unroll
    for (int s = 1; s < SPLITK; ++s) {
        const float v  = pd[s * N_PTS + p];
        const int   vi = pi[s * N_PTS + p];
        if (v < bb || (v == bb && vi < bi)) { bb = v; bi = vi; }
    }
    out[p] = bi;
}

extern "C" void kernel_launch(void* const* d_in, const int* in_sizes, int n_in,
                              void* d_out, int out_size, void* d_ws, size_t ws_size,
                              hipStream_t stream) {
    const float* x    = (const float*)d_in[0];
    const float* vecs = (const float*)d_in[1];
    int* out = (int*)d_out;
    char* ws = (char*)d_ws;

    if (ws_size >= (size_t)WS_END) {
        _Float16* xh = (_Float16*)(ws + WS_XH);
        _Float16* xl = (_Float16*)(ws + WS_XL);
        _Float16* ch = (_Float16*)(ws + WS_CH);
        _Float16* cl = (_Float16*)(ws + WS_CL);
        float* c2 = (float*)(ws + WS_C2);
        float* pd = (float*)(ws + WS_PD);
        int*   pi = (int*)(ws + WS_PI);

        hipLaunchKernelGGL(prep_kernel, dim3(XBLOCKS + CBLOCKS), dim3(256), 0, stream,
                           x, vecs, xh, xl, ch, cl, c2);
        hipLaunchKernelGGL(vq_main_fast, dim3((N_PTS / TM) * SPLITK), dim3(256), 0, stream,
                           xh, xl, ch, cl, c2, pd, pi);
        hipLaunchKernelGGL(vq_combine, dim3(N_PTS / 256), dim3(256), 0, stream,
                           pd, pi, out);
    } else {
        float* c2 = (float*)ws;
        float* pd = (float*)ws + K_CB;
        int*   pi = (int*)((float*)ws + K_CB + SPLITK * N_PTS);
        hipLaunchKernelGGL(cnorms_kernel, dim3(K_CB / 4), dim3(256), 0, stream,
                           vecs, c2);
        hipLaunchKernelGGL(vq_main_v3, dim3((N_PTS / TM) * SPLITK), dim3(256), 0, stream,
                           x, vecs, c2, pd, pi);
        hipLaunchKernelGGL(vq_combine, dim3(N_PTS / 256), dim3(256), 0, stream,
                           pd, pi, out);
    }
}

// Round 2
// 501.379 us; speedup vs baseline: 1.1063x; 1.1063x over previous
//
#include <hip/hip_runtime.h>
#include <stdint.h>
#include <stddef.h>

// VectorQuantization — N=32768, K=8192, D=256 fp32 -> int32 argmin.
// Round 6: round-5 double-buffer pipeline KEPT, LDS bank conflicts FIXED.
// Round 5's linear 64B-row layout was an 8-way conflict on ds_read_b128
// (column = (row&1, g): 8 lanes per 16B column) -> SQ_LDS_BANK_CONFLICT 3.4e7.
// Fix: XOR k-slot swizzle with key (row>>1)&3, applied on BOTH sides:
//   - stage: pre-swizzled GLOBAL source (DMA dest linear, as required),
//     lane i fetches k-slot (i&3) ^ ((i>>3)&3) of row i>>2
//   - read: slot = g ^ ((fr>>1)&3)
// Per 16-lane quarter this covers all 8 16B columns of the 128B bank line
// with exactly 2 lanes each (2-way = free), same structure round 4 measured
// conflict-free. K-slice accumulation order unchanged -> bit-identical.
// Fallback to the (passing) round-3 kernel if ws_size < 43MB.

#define N_PTS 32768
#define K_CB  8192
#define D_DIM 256
#define TM 128
#define TN 128
#define SPLITK 4
#define KCHUNK (K_CB / SPLITK)   // 2048
#define NTILES (KCHUNK / TN)     // 16
#define NCHUNKS (NTILES * 8)     // 128 BK=32 chunks per block

// fast-path ws layout (byte offsets; all 16B-aligned)
#define WS_XH   0
#define WS_XL   (WS_XH + N_PTS * D_DIM * 2)
#define WS_CH   (WS_XL + N_PTS * D_DIM * 2)
#define WS_CL   (WS_CH + K_CB * D_DIM * 2)
#define WS_C2   (WS_CL + K_CB * D_DIM * 2)
#define WS_PD   (WS_C2 + K_CB * 4)
#define WS_PI   (WS_PD + SPLITK * N_PTS * 4)
#define WS_END  (WS_PI + SPLITK * N_PTS * 4)   // 43,024,384 B

typedef _Float16 half4v __attribute__((ext_vector_type(4)));
typedef _Float16 half8v __attribute__((ext_vector_type(8)));
typedef float    f32x4  __attribute__((ext_vector_type(4)));

__device__ __forceinline__ void gld16(const void* g, void* l) {
    __builtin_amdgcn_global_load_lds(
        (const __attribute__((address_space(1))) void*)g,
        (__attribute__((address_space(3))) void*)l, 16, 0, 0);
}

// ---------------- preprocessing (fused: split x, split codes + norms) ------

#define XBLOCKS (N_PTS * D_DIM / 4 / 256)   // 8192
#define CBLOCKS (K_CB * D_DIM / 4 / 256)    // 2048

__global__ void __launch_bounds__(256)
prep_kernel(const float* __restrict__ x, const float* __restrict__ vecs,
            _Float16* __restrict__ xh, _Float16* __restrict__ xl,
            _Float16* __restrict__ ch, _Float16* __restrict__ cl,
            float* __restrict__ c2) {
    const int b = blockIdx.x;
    if (b < XBLOCKS) {
        const int i = b * 256 + threadIdx.x;           // one float4 per thread
        const float4 v = ((const float4*)x)[i];
        half4v h = {(_Float16)v.x, (_Float16)v.y, (_Float16)v.z, (_Float16)v.w};
        half4v l = {(_Float16)((v.x - (float)h[0]) * 2048.0f),
                    (_Float16)((v.y - (float)h[1]) * 2048.0f),
                    (_Float16)((v.z - (float)h[2]) * 2048.0f),
                    (_Float16)((v.w - (float)h[3]) * 2048.0f)};
        *(half4v*)(xh + (size_t)i * 4) = h;
        *(half4v*)(xl + (size_t)i * 4) = l;
    } else {
        const int i = (b - XBLOCKS) * 256 + threadIdx.x;
        const float4 v = ((const float4*)vecs)[i];
        half4v h = {(_Float16)v.x, (_Float16)v.y, (_Float16)v.z, (_Float16)v.w};
        half4v l = {(_Float16)((v.x - (float)h[0]) * 2048.0f),
                    (_Float16)((v.y - (float)h[1]) * 2048.0f),
                    (_Float16)((v.z - (float)h[2]) * 2048.0f),
                    (_Float16)((v.w - (float)h[3]) * 2048.0f)};
        *(half4v*)(ch + (size_t)i * 4) = h;
        *(half4v*)(cl + (size_t)i * 4) = l;
        // one wave == one code row (64 lanes x float4 = 256 floats) -> norm.
        // identical reduction tree to round-4 cnorms_kernel (bit-identical c2).
        float s = v.x * v.x + v.y * v.y + v.z * v.z + v.w * v.w;
#pragma unroll
        for (int off = 32; off > 0; off >>= 1) s += __shfl_down(s, off, 64);
        if ((threadIdx.x & 63) == 0) c2[i >> 6] = s;
    }
}

// kept for the fallback path
__global__ void __launch_bounds__(256)
cnorms_kernel(const float* __restrict__ vecs, float* __restrict__ c2) {
    int gwave = (blockIdx.x * 256 + threadIdx.x) >> 6;   // one wave per code row
    int lane  = threadIdx.x & 63;
    const float* src = vecs + (size_t)gwave * D_DIM;
    float4 v = ((const float4*)src)[lane];
    float s = v.x * v.x + v.y * v.y + v.z * v.z + v.w * v.w;
#pragma unroll
    for (int off = 32; off > 0; off >>= 1) s += __shfl_down(s, off, 64);
    if (lane == 0) c2[gwave] = s;
}

// ---------------- fast main kernel ----------------

__global__ void __launch_bounds__(256, 2)
vq_main_fast(const _Float16* __restrict__ xh_g, const _Float16* __restrict__ xl_g,
             const _Float16* __restrict__ ch_g, const _Float16* __restrict__ cl_g,
             const float* __restrict__ c2, float* __restrict__ pd, int* __restrict__ pi) {
    // two 32KB buffers; per buffer: xh [0,8K) xl [8K,16K) ch [16K,24K) cl [24K,32K)
    // rows are 64B (32 halves); k-slot s of row r holds k-group s ^ ((r>>1)&3).
    __shared__ __align__(16) char lds[65536];

    const int t    = threadIdx.x;
    const int lane = t & 63;
    const int wv   = t >> 6;
    const int wy   = wv >> 1, wx = wv & 1;   // wave quadrant of 128x128
    const int fr   = lane & 15;              // row/col within 16x16 tile
    const int g    = lane >> 4;              // k-group 0..3

    const int split = blockIdx.x & (SPLITK - 1);
    const int pbase = (blockIdx.x >> 2) * TM;
    const int kbase = split * KCHUNK;

    // staging: one gld16 covers 16 rows x 64B. DMA dest is linear (lane*16);
    // the swizzle is baked into the per-lane GLOBAL source: lane i fetches
    // k-slot (i&3) ^ ((i>>3)&3) of row i>>2 (key (row>>1)&3; wave/q/chunk
    // bases are all =0 mod 4 in row>>1 so one formula covers everything).
    const int srowoff = (lane >> 2) * (D_DIM * 2)
                      + ((((lane & 3) ^ ((lane >> 3) & 3))) << 4);
    const char* xh_s = (const char*)xh_g + (size_t)(pbase + wv * 32) * (D_DIM * 2) + srowoff;
    const char* xl_s = (const char*)xl_g + (size_t)(pbase + wv * 32) * (D_DIM * 2) + srowoff;
    const char* ch_s = (const char*)ch_g + (size_t)(kbase + wv * 32) * (D_DIM * 2) + srowoff;
    const char* cl_s = (const char*)cl_g + (size_t)(kbase + wv * 32) * (D_DIM * 2) + srowoff;
    const int stA = wv * 32 * 64;            // wave staging base within a region

    // fragment LDS byte offsets (within a buffer): row*64 + swizzled slot.
    // key (row>>1)&3 reduces to (fr>>1)&3 (row base is a multiple of 16).
    // Per 16-lane quarter: (fr&1, g^((fr>>1)&3)) covers all 8 16B columns of
    // the 128B bank line with exactly 2 lanes each -> conflict-free b128.
    const int skey = (fr >> 1) & 3;
    int aoff[4], boff[4];
#pragma unroll
    for (int i = 0; i < 4; ++i) {
        aoff[i] = (wy * 64 + i * 16 + fr) * 64 + ((g ^ skey) << 4);
        boff[i] = 16384 + (wx * 64 + i * 16 + fr) * 64 + ((g ^ skey) << 4);
    }

    f32x4 acc[4][4];

    // chunk c = kt*8 + dkc; buffer parity = c&1. 8 gld16 per wave per chunk.
    auto STAGE = [&](char* L, int c) {
        const size_t kofs = (size_t)(c >> 3) * (TN * D_DIM * 2);   // kt tile
        const int gofs = (c & 7) * 64;                             // byte offset in row
#pragma unroll
        for (int q = 0; q < 2; ++q) {
            gld16(xh_s + q * 8192 + gofs, L +         stA + q * 1024);
            gld16(xl_s + q * 8192 + gofs, L +  8192 + stA + q * 1024);
            gld16(ch_s + kofs + q * 8192 + gofs, L + 16384 + stA + q * 1024);
            gld16(cl_s + kofs + q * 8192 + gofs, L + 24576 + stA + q * 1024);
        }
    };

    auto COMPUTE = [&](const char* L) {
        half8v a1[4], a2[4], a3[4];
#pragma unroll
        for (int i = 0; i < 4; ++i) {
            const char* p = L + aoff[i];
            a1[i] = *(const half8v*)p;                  // xh
            a3[i] = *(const half8v*)(p + 8192);         // xl*2^11
            a2[i] = a1[i] * (_Float16)4.8828125e-4f;    // xh*2^-11
        }
#pragma unroll
        for (int j = 0; j < 4; ++j) {
            const char* p = L + boff[j];
            half8v b1 = *(const half8v*)p;              // ch
            half8v b2 = *(const half8v*)(p + 8192);     // cl*2^11
            half8v b3 = b1 * (_Float16)4.8828125e-4f;   // ch*2^-11
#pragma unroll
            for (int i = 0; i < 4; ++i) {
                acc[i][j] = __builtin_amdgcn_mfma_f32_16x16x32_f16(a1[i], b1, acc[i][j], 0, 0, 0);
                acc[i][j] = __builtin_amdgcn_mfma_f32_16x16x32_f16(a2[i], b2, acc[i][j], 0, 0, 0);
                acc[i][j] = __builtin_amdgcn_mfma_f32_16x16x32_f16(a3[i], b3, acc[i][j], 0, 0, 0);
            }
        }
    };

    float best[16];
    int   bidx[16];
#pragma unroll
    for (int i = 0; i < 16; ++i) { best[i] = 3.4e38f; bidx[i] = 0; }

    STAGE(lds, 0);
    __syncthreads();

#pragma unroll 1
    for (int kt = 0; kt < NTILES; ++kt) {
#pragma unroll
        for (int i = 0; i < 4; ++i)
#pragma unroll
            for (int j = 0; j < 4; ++j) {
                f32x4 z = {0.f, 0.f, 0.f, 0.f};
                acc[i][j] = z;
            }

#pragma unroll 1
        for (int du = 0; du < 4; ++du) {
            const int c = kt * 8 + du * 2;
            // even chunk: compute buf0 while buf1's data flies in
            if (c + 1 < NCHUNKS) STAGE(lds + 32768, c + 1);
            COMPUTE(lds);
            __syncthreads();                  // drains vmcnt: c+1 is ready
            // odd chunk: compute buf1 while buf0's data flies in
            if (c + 2 < NCHUNKS) STAGE(lds, c + 2);
            COMPUTE(lds + 32768);
            __syncthreads();                  // drains vmcnt: c+2 is ready
        }

        // merge tile into running argmin; ascending j + strict < == np first-min
        const int ktbase = kbase + kt * TN;
#pragma unroll
        for (int j = 0; j < 4; ++j) {
            const int cg = ktbase + wx * 64 + j * 16 + fr;
            const float c2v = c2[cg];
#pragma unroll
            for (int i = 0; i < 4; ++i)
#pragma unroll
                for (int r = 0; r < 4; ++r) {
                    const float v = fmaf(-2.0f, acc[i][j][r], c2v);
                    const int s = i * 4 + r;
                    if (v < best[s]) { best[s] = v; bidx[s] = cg; }
                }
        }
    }

    // reduce across the 16 lanes holding each point row, then the 2 wave-cols
    __syncthreads();
    float* rd = (float*)lds;          // 128 x 2 floats
    int*   ri = (int*)lds + 256;      // 128 x 2 ints
#pragma unroll
    for (int i = 0; i < 4; ++i)
#pragma unroll
        for (int r = 0; r < 4; ++r) {
            float bv = best[i * 4 + r];
            int   bi = bidx[i * 4 + r];
#pragma unroll
            for (int off = 1; off < 16; off <<= 1) {
                const float ov = __shfl_xor(bv, off, 64);
                const int   oi = __shfl_xor(bi, off, 64);
                if (ov < bv || (ov == bv && oi < bi)) { bv = ov; bi = oi; }
            }
            if (fr == 0) {
                const int rowl = wy * 64 + i * 16 + g * 4 + r;
                rd[rowl * 2 + wx] = bv;
                ri[rowl * 2 + wx] = bi;
            }
        }
    __syncthreads();
    if (t < TM) {
        float b0 = rd[t * 2];
        int   i0 = ri[t * 2];
        const float b1 = rd[t * 2 + 1];
        const int   i1 = ri[t * 2 + 1];
        if (b1 < b0 || (b1 == b0 && i1 < i0)) { b0 = b1; i0 = i1; }
        pd[split * N_PTS + pbase + t] = b0;
        pi[split * N_PTS + pbase + t] = i0;
    }
}

// ---------------- fallback (round-3, passing) ----------------

#define BK 32
#define LS (BK + 4)

__device__ inline half8v load8(const _Float16* p) {
    half4v a = *(const half4v*)p;
    half4v b = *(const half4v*)(p + 4);
    return __builtin_shufflevector(a, b, 0, 1, 2, 3, 4, 5, 6, 7);
}

struct Trip { _Float16 h, s2, l2; };

__device__ inline Trip cvt3(float v) {
    Trip t;
    _Float16 hh = (_Float16)v;
    float hf = (float)hh;
    t.h  = hh;
    t.s2 = (_Float16)(hf * 4.8828125e-4f);
    t.l2 = (_Float16)((v - hf) * 2048.0f);
    return t;
}

__global__ void __launch_bounds__(256, 2)
vq_main_v3(const float* __restrict__ x, const float* __restrict__ vecs,
           const float* __restrict__ c2, float* __restrict__ pd, int* __restrict__ pi) {
    __shared__ _Float16 lds[6 * TM * LS];
    _Float16* xh  = lds;
    _Float16* xs2 = lds + 1 * TM * LS;
    _Float16* xl2 = lds + 2 * TM * LS;
    _Float16* ch  = lds + 3 * TM * LS;
    _Float16* cl2 = lds + 4 * TM * LS;
    _Float16* cs2 = lds + 5 * TM * LS;

    const int t     = threadIdx.x;
    const int split = blockIdx.x & (SPLITK - 1);
    const int pbase = (blockIdx.x >> 2) * TM;
    const int kbase = split * KCHUNK;

    const int lane = t & 63;
    const int wv   = t >> 6;
    const int wy   = wv >> 1, wx = wv & 1;
    const int fr   = lane & 15;
    const int g    = lane >> 4;
    const int kb   = g * 8;

    const int srow = t >> 3;
    const int sc4  = (t & 7) * 4;

    float best[16];
    int   bidx[16];
#pragma unroll
    for (int i = 0; i < 16; ++i) { best[i] = 3.4e38f; bidx[i] = 0; }

    for (int kt = 0; kt < NTILES; ++kt) {
        const int ktbase = kbase + kt * TN;
        f32x4 acc[4][4];
#pragma unroll
        for (int i = 0; i < 4; ++i)
#pragma unroll
            for (int j = 0; j < 4; ++j) {
                f32x4 z = {0.f, 0.f, 0.f, 0.f};
                acc[i][j] = z;
            }
        for (int dk = 0; dk < D_DIM; dk += BK) {
            __syncthreads();
#pragma unroll
            for (int p = 0; p < 4; ++p) {
                const int row = srow + p * 32;
                const float4 v = *(const float4*)&x[(size_t)(pbase + row) * D_DIM + dk + sc4];
                const Trip t0 = cvt3(v.x), t1 = cvt3(v.y), t2 = cvt3(v.z), t3 = cvt3(v.w);
                half4v h  = {t0.h,  t1.h,  t2.h,  t3.h};
                half4v s2 = {t0.s2, t1.s2, t2.s2, t3.s2};
                half4v l2 = {t0.l2, t1.l2, t2.l2, t3.l2};
                *(half4v*)&xh [row * LS + sc4] = h;
                *(half4v*)&xs2[row * LS + sc4] = s2;
                *(half4v*)&xl2[row * LS + sc4] = l2;
                const float4 w = *(const float4*)&vecs[(size_t)(ktbase + row) * D_DIM + dk + sc4];
                const Trip u0 = cvt3(w.x), u1 = cvt3(w.y), u2 = cvt3(w.z), u3 = cvt3(w.w);
                half4v hc = {u0.h,  u1.h,  u2.h,  u3.h};
                half4v sc = {u0.s2, u1.s2, u2.s2, u3.s2};
                half4v lc = {u0.l2, u1.l2, u2.l2, u3.l2};
                *(half4v*)&ch [row * LS + sc4] = hc;
                *(half4v*)&cs2[row * LS + sc4] = sc;
                *(half4v*)&cl2[row * LS + sc4] = lc;
            }
            __syncthreads();
            half8v a1[4], a2[4], a3[4], b1[4], b2[4], b3[4];
#pragma unroll
            for (int i = 0; i < 4; ++i) {
                const int aoff = (wy * 64 + i * 16 + fr) * LS + kb;
                a1[i] = load8(&xh [aoff]);
                a2[i] = load8(&xs2[aoff]);
                a3[i] = load8(&xl2[aoff]);
                const int boff2 = (wx * 64 + i * 16 + fr) * LS + kb;
                b1[i] = load8(&ch [boff2]);
                b2[i] = load8(&cl2[boff2]);
                b3[i] = load8(&cs2[boff2]);
            }
#pragma unroll
            for (int i = 0; i < 4; ++i)
#pragma unroll
                for (int j = 0; j < 4; ++j) {
                    acc[i][j] = __builtin_amdgcn_mfma_f32_16x16x32_f16(a1[i], b1[j], acc[i][j], 0, 0, 0);
                    acc[i][j] = __builtin_amdgcn_mfma_f32_16x16x32_f16(a2[i], b2[j], acc[i][j], 0, 0, 0);
                    acc[i][j] = __builtin_amdgcn_mfma_f32_16x16x32_f16(a3[i], b3[j], acc[i][j], 0, 0, 0);
                }
        }
#pragma unroll
        for (int j = 0; j < 4; ++j) {
            const int cg = ktbase + wx * 64 + j * 16 + fr;
            const float c2v = c2[cg];
#pragma unroll
            for (int i = 0; i < 4; ++i)
#pragma unroll
                for (int r = 0; r < 4; ++r) {
                    const float v = fmaf(-2.0f, acc[i][j][r], c2v);
                    const int s = i * 4 + r;
                    if (v < best[s]) { best[s] = v; bidx[s] = cg; }
                }
        }
    }
    __syncthreads();
    float* rd = (float*)lds;
    int*   ri = (int*)lds + 256;
#pragma unroll
    for (int i = 0; i < 4; ++i)
#pragma unroll
        for (int r = 0; r < 4; ++r) {
            float bv = best[i * 4 + r];
            int   bi = bidx[i * 4 + r];
#pragma unroll
            for (int off = 1; off < 16; off <<= 1) {
                const float ov = __shfl_xor(bv, off, 64);
                const int   oi = __shfl_xor(bi, off, 64);
                if (ov < bv || (ov == bv && oi < bi)) { bv = ov; bi = oi; }
            }
            if (fr == 0) {
                const int rowl = wy * 64 + i * 16 + g * 4 + r;
                rd[rowl * 2 + wx] = bv;
                ri[rowl * 2 + wx] = bi;
            }
        }
    __syncthreads();
    if (t < TM) {
        float b0 = rd[t * 2];
        int   i0 = ri[t * 2];
        const float b1 = rd[t * 2 + 1];
        const int   i1 = ri[t * 2 + 1];
        if (b1 < b0 || (b1 == b0 && i1 < i0)) { b0 = b1; i0 = i1; }
        pd[split * N_PTS + pbase + t] = b0;
        pi[split * N_PTS + pbase + t] = i0;
    }
}

// ---------------- combine ----------------

__global__ void __launch_bounds__(256)
vq_combine(const float* __restrict__ pd, const int* __restrict__ pi,
           int* __restrict__ out) {
    const int p = blockIdx.x * 256 + threadIdx.x;
    float bb = pd[p];
    int   bi = pi[p];
#pragma unroll
    for (int s = 1; s < SPLITK; ++s) {
        const float v  = pd[s * N_PTS + p];
        const int   vi = pi[s * N_PTS + p];
        if (v < bb || (v == bb && vi < bi)) { bb = v; bi = vi; }
    }
    out[p] = bi;
}

extern "C" void kernel_launch(void* const* d_in, const int* in_sizes, int n_in,
                              void* d_out, int out_size, void* d_ws, size_t ws_size,
                              hipStream_t stream) {
    const float* x    = (const float*)d_in[0];
    const float* vecs = (const float*)d_in[1];
    int* out = (int*)d_out;
    char* ws = (char*)d_ws;

    if (ws_size >= (size_t)WS_END) {
        _Float16* xh = (_Float16*)(ws + WS_XH);
        _Float16* xl = (_Float16*)(ws + WS_XL);
        _Float16* ch = (_Float16*)(ws + WS_CH);
        _Float16* cl = (_Float16*)(ws + WS_CL);
        float* c2 = (float*)(ws + WS_C2);
        float* pd = (float*)(ws + WS_PD);
        int*   pi = (int*)(ws + WS_PI);

        hipLaunchKernelGGL(prep_kernel, dim3(XBLOCKS + CBLOCKS), dim3(256), 0, stream,
                           x, vecs, xh, xl, ch, cl, c2);
        hipLaunchKernelGGL(vq_main_fast, dim3((N_PTS / TM) * SPLITK), dim3(256), 0, stream,
                           xh, xl, ch, cl, c2, pd, pi);
        hipLaunchKernelGGL(vq_combine, dim3(N_PTS / 256), dim3(256), 0, stream,
                           pd, pi, out);
    } else {
        float* c2 = (float*)ws;
        float* pd = (float*)ws + K_CB;
        int*   pi = (int*)((float*)ws + K_CB + SPLITK * N_PTS);
        hipLaunchKernelGGL(cnorms_kernel, dim3(K_CB / 4), dim3(256), 0, stream,
                           vecs, c2);
        hipLaunchKernelGGL(vq_main_v3, dim3((N_PTS / TM) * SPLITK), dim3(256), 0, stream,
                           x, vecs, c2, pd, pi);
        hipLaunchKernelGGL(vq_combine, dim3(N_PTS / 256), dim3(256), 0, stream,
                           pd, pi, out);
    }
}